// Round 9
// baseline (415.661 us; speedup 1.0000x reference)
//
#include <hip/hip_runtime.h>
#include <stdint.h>
#include <math.h>

#define NALPH 128
#define NEMB  128
#define NST   512
#define BATCH 256
#define TLEN  256
#define FANIN 640   // NEMB + NST

#if __has_builtin(__builtin_amdgcn_sdot4)
#define SDOT4(a, b, c) __builtin_amdgcn_sdot4((a), (b), (c), false)
#else
__device__ __forceinline__ int SDOT4(int a, int b, int c) {
  c += (int)(signed char)(a)       * (int)(signed char)(b);
  c += (int)(signed char)(a >> 8)  * (int)(signed char)(b >> 8);
  c += (int)(signed char)(a >> 16) * (int)(signed char)(b >> 16);
  c += (int)(signed char)(a >> 24) * (int)(signed char)(b >> 24);
  return c;
}
#endif

// swap adjacent lanes (2k <-> 2k+1): DPP quad_perm(1,0,3,2) = 0xB1
__device__ __forceinline__ int dpp_xor1(int v) {
  return __builtin_amdgcn_update_dpp(0, v, 0xB1, 0xF, 0xF, true);
}

// ---------------------------------------------------------------------------
// k_prep (896 blocks x 256 thr):
//  [0,256)    G[tok*512+n] = b_in[n] + sum_e emb[tok,e]*W_in[n,e]  (fp32 exact)
//  [256,768)  W_s row n quant -> WqI[j*1024 + n*2 + h]  (j in [0,64) dword of
//             K-half h), Sd[n] = rowmax/16129    [R4 layout, field-proven]
//  [768,896)  W_out row-quant: WoQ[j*128+a] = pack4 i8, So[a] = mx/16129
// ---------------------------------------------------------------------------
__global__ __launch_bounds__(256) void k_prep(
    const float* __restrict__ emb, const float* __restrict__ W_in,
    const float* __restrict__ b_in, const float* __restrict__ W_out,
    float* __restrict__ G, int* __restrict__ WqI, float* __restrict__ Sd,
    int* __restrict__ WoQ, float* __restrict__ So)
{
  int bid = blockIdx.x, tid = threadIdx.x;
  if (bid < 256) {
    int idx = bid * 256 + tid;           // tok*512 + n
    int tok = idx >> 9, n = idx & 511;
    const float* er = emb + tok * NEMB;
    const float* wr = W_in + (size_t)n * FANIN;
    float acc = b_in[n];
#pragma unroll 8
    for (int e = 0; e < NEMB; ++e) acc += er[e] * wr[e];
    G[idx] = acc;
  } else if (bid < 768) {
    int n = bid - 256;                   // W_s row
    __shared__ float smax[128];
    float lw[4]; float m = 0.f;
    if (tid < 128) {
      const float* wr = W_in + (size_t)n * FANIN + NEMB + tid * 4;
#pragma unroll
      for (int i = 0; i < 4; ++i) { lw[i] = wr[i]; m = fmaxf(m, fabsf(lw[i])); }
      smax[tid] = m;
    }
    __syncthreads();
    for (int s2 = 64; s2 > 0; s2 >>= 1) {
      if (tid < s2) smax[tid] = fmaxf(smax[tid], smax[tid + s2]);
      __syncthreads();
    }
    float mx = smax[0];
    if (tid < 128) {
      float r = 127.f / mx;
      uint32_t pk = 0;
#pragma unroll
      for (int i = 0; i < 4; ++i) {
        int qv = (int)rintf(lw[i] * r);
        qv = qv < -127 ? -127 : (qv > 127 ? 127 : qv);
        pk |= (uint32_t)(qv & 0xff) << (8 * i);
      }
      int h = tid >> 6, j = tid & 63;    // byte range tid*4 -> half h, dword j
      WqI[j * 1024 + (n << 1) + h] = (int)pk;
    }
    if (tid == 0) Sd[n] = mx / 16129.0f;
  } else {
    int a = bid - 768;                   // W_out row
    __shared__ float smax[128];
    float lw[4]; float m = 0.f;
    if (tid < 128) {
      const float* wr = W_out + (size_t)a * NST + tid * 4;
#pragma unroll
      for (int i = 0; i < 4; ++i) { lw[i] = wr[i]; m = fmaxf(m, fabsf(lw[i])); }
      smax[tid] = m;
    }
    __syncthreads();
    for (int s2 = 64; s2 > 0; s2 >>= 1) {
      if (tid < s2) smax[tid] = fmaxf(smax[tid], smax[tid + s2]);
      __syncthreads();
    }
    float mx = smax[0];
    if (tid < 128) {
      float r = 127.f / mx;
      uint32_t pk = 0;
#pragma unroll
      for (int i = 0; i < 4; ++i) {
        int qv = (int)rintf(lw[i] * r);
        qv = qv < -127 ? -127 : (qv > 127 ? 127 : qv);
        pk |= (uint32_t)(qv & 0xff) << (8 * i);
      }
      WoQ[tid * 128 + a] = (int)pk;      // k_out reads WoQ[j*128+a] coalesced
    }
    if (tid == 0) So[a] = mx / 16129.0f;
  }
}

// ---------------------------------------------------------------------------
// k_rec: 256 blocks x 1024 threads (16 waves/CU = 4/EU -> 2x latency hiding
// vs R8's single 8-wave block). Lane-pair K-split: thread t -> column n=t>>1,
// K-half h=t&1 (adjacent lanes). wq[64] i8 dwords register-resident (~100
// live regs < 128 cap). Per step: 16 broadcast ds_read_b128 + 64 sdot4 in 4
// chains; cross-half reduce = one DPP-pair add (R4 field-proven numerics).
// ONE barrier/step. States copied to global post-barrier (128 thr, dwords).
// ---------------------------------------------------------------------------
__global__ __launch_bounds__(1024, 4) void k_rec(
    const int* __restrict__ w, const float* __restrict__ G,
    const int* __restrict__ WqI, const float* __restrict__ Sd,
    signed char* __restrict__ qstates)
{
  __shared__ __align__(16) signed char qs[2][NST];
  int t = threadIdx.x;
  int row = blockIdx.x;
  int n = t >> 1;                        // column (shared by lane pair)
  int h = t & 1;                         // K-half
  int h256 = h << 8;

  int wq[64];
#pragma unroll
  for (int j = 0; j < 64; ++j) wq[j] = WqI[j * 1024 + t];   // coalesced
  float dn = Sd[n];

  if (t < 128) ((int*)&qs[0][0])[t] = 0;
  __syncthreads();

  const int* wr = w + row * TLEN;
  int* qbase = (int*)(qstates + (size_t)row * TLEN * NST);

  float g = G[wr[0] * NST + n];
  int p = 0;
  for (int tt = 0; tt < TLEN; ++tt) {
    int tok_n = (tt < TLEN - 1) ? wr[tt + 1] : 0;
    float g_n = G[tok_n * NST + n];      // prefetch next step's fin
    const int4* sp = (const int4*)(&qs[0][0] + (p << 9) + h256);
    int a0 = 0, a1 = 0, a2 = 0, a3 = 0;  // 4 independent chains, 16 deep
#pragma unroll
    for (int j = 0; j < 4; ++j) {
      int4 s0 = sp[4 * j + 0];
      int4 s1 = sp[4 * j + 1];
      int4 s2 = sp[4 * j + 2];
      int4 s3 = sp[4 * j + 3];
      a0 = SDOT4(wq[16 * j +  0], s0.x, a0);
      a1 = SDOT4(wq[16 * j +  1], s0.y, a1);
      a2 = SDOT4(wq[16 * j +  2], s0.z, a2);
      a3 = SDOT4(wq[16 * j +  3], s0.w, a3);
      a0 = SDOT4(wq[16 * j +  4], s1.x, a0);
      a1 = SDOT4(wq[16 * j +  5], s1.y, a1);
      a2 = SDOT4(wq[16 * j +  6], s1.z, a2);
      a3 = SDOT4(wq[16 * j +  7], s1.w, a3);
      a0 = SDOT4(wq[16 * j +  8], s2.x, a0);
      a1 = SDOT4(wq[16 * j +  9], s2.y, a1);
      a2 = SDOT4(wq[16 * j + 10], s2.z, a2);
      a3 = SDOT4(wq[16 * j + 11], s2.w, a3);
      a0 = SDOT4(wq[16 * j + 12], s3.x, a0);
      a1 = SDOT4(wq[16 * j + 13], s3.y, a1);
      a2 = SDOT4(wq[16 * j + 14], s3.z, a2);
      a3 = SDOT4(wq[16 * j + 15], s3.w, a3);
    }
    int ar = (a0 + a1) + (a2 + a3);
    ar += dpp_xor1(ar);                  // full 512-K dot in both lanes

    float a = fmaf((float)ar, dn, g);
    float e = __expf(2.f * a);           // tanh = 1 - 2/(e^(2a)+1); saturates
    float s = fmaf(-2.f, __builtin_amdgcn_rcpf(e + 1.f), 1.f);
    signed char q8 = (signed char)(int)rintf(s * 127.f);
    if (h == 0) qs[p ^ 1][n] = q8;
    __syncthreads();                     // the one barrier per step
    if (t < 128) qbase[(tt << 7) + t] = ((const int*)&qs[0][0])[(p ^ 1) * 128 + t];
    g = g_n;
    p ^= 1;
  }
}

// ---------------------------------------------------------------------------
// k_out_i8 (verbatim R8): y[bt,a] = b_out[a] + So[a]*sum_k qs[bt,k]*qw[a,k]
// 2048 blocks x 256 thr. Block: 32 bt-rows x 128 a. LDS-staged states,
// broadcast b128 reads, 16 sdot4 per j4.
// ---------------------------------------------------------------------------
__global__ __launch_bounds__(256) void k_out_i8(
    const signed char* __restrict__ qstates, const int* __restrict__ WoQ,
    const float* __restrict__ So, const float* __restrict__ b_out,
    float* __restrict__ y)
{
  __shared__ __align__(16) int sl[32 * 128];   // 16 KB
  int tid = threadIdx.x;
  size_t bt0 = (size_t)blockIdx.x * 32;
  const int4* gp = (const int4*)(qstates + bt0 * NST);
  int4* slp = (int4*)sl;
#pragma unroll
  for (int i = 0; i < 4; ++i) slp[tid + 256 * i] = gp[tid + 256 * i];
  __syncthreads();

  int a0 = tid & 63, gidx = tid >> 6;    // gidx uniform per wave
  const int* slg = sl + gidx * 8 * 128;
  int acc0[8], acc1[8];
#pragma unroll
  for (int r = 0; r < 8; ++r) { acc0[r] = 0; acc1[r] = 0; }

  for (int j4 = 0; j4 < 32; ++j4) {
    int w00 = WoQ[(4 * j4 + 0) * 128 + a0];
    int w01 = WoQ[(4 * j4 + 0) * 128 + a0 + 64];
    int w10 = WoQ[(4 * j4 + 1) * 128 + a0];
    int w11 = WoQ[(4 * j4 + 1) * 128 + a0 + 64];
    int w20 = WoQ[(4 * j4 + 2) * 128 + a0];
    int w21 = WoQ[(4 * j4 + 2) * 128 + a0 + 64];
    int w30 = WoQ[(4 * j4 + 3) * 128 + a0];
    int w31 = WoQ[(4 * j4 + 3) * 128 + a0 + 64];
#pragma unroll
    for (int r = 0; r < 8; ++r) {
      int4 s = *(const int4*)&slg[r * 128 + 4 * j4];  // broadcast b128
      acc0[r] = SDOT4(w00, s.x, acc0[r]);
      acc1[r] = SDOT4(w01, s.x, acc1[r]);
      acc0[r] = SDOT4(w10, s.y, acc0[r]);
      acc1[r] = SDOT4(w11, s.y, acc1[r]);
      acc0[r] = SDOT4(w20, s.z, acc0[r]);
      acc1[r] = SDOT4(w21, s.z, acc1[r]);
      acc0[r] = SDOT4(w30, s.w, acc0[r]);
      acc1[r] = SDOT4(w31, s.w, acc1[r]);
    }
  }

  float s0 = So[a0], s1 = So[a0 + 64];
  float b0 = b_out[a0], b1 = b_out[a0 + 64];
#pragma unroll
  for (int r = 0; r < 8; ++r) {
    size_t rowb = (bt0 + gidx * 8 + r) * 128;
    y[rowb + a0]      = (float)acc0[r] * s0 + b0;
    y[rowb + a0 + 64] = (float)acc1[r] * s1 + b1;
  }
}

// ---------------------------------------------------------------------------
extern "C" void kernel_launch(void* const* d_in, const int* in_sizes, int n_in,
                              void* d_out, int out_size, void* d_ws, size_t ws_size,
                              hipStream_t stream) {
  const int*   w     = (const int*)d_in[0];
  const float* emb   = (const float*)d_in[1];
  const float* W_in  = (const float*)d_in[2];
  const float* b_in  = (const float*)d_in[3];
  const float* W_out = (const float*)d_in[4];
  const float* b_out = (const float*)d_in[5];
  float* y = (float*)d_out;

  char* ws = (char*)d_ws;
  float*       G       = (float*)ws;                        // 256 KB
  int*         WqI     = (int*)(ws + (256 << 10));          // 256 KB
  float*       Sd      = (float*)(ws + (512 << 10));        // 2 KB
  int*         WoQ     = (int*)(ws + (576 << 10));          // 64 KB
  float*       So      = (float*)(ws + (640 << 10));        // 0.5 KB
  signed char* qstates = (signed char*)(ws + (1024 << 10)); // 32 MB i8

  k_prep  <<<896, 256, 0, stream>>>(emb, W_in, b_in, W_out, G, WqI, Sd, WoQ, So);
  k_rec   <<<BATCH, 1024, 0, stream>>>(w, G, WqI, Sd, qstates);
  k_out_i8<<<BATCH * TLEN / 32, 256, 0, stream>>>(qstates, WoQ, So, b_out, y);
}

// Round 10
// 354.177 us; speedup vs baseline: 1.1736x; 1.1736x over previous
//
#include <hip/hip_runtime.h>
#include <stdint.h>
#include <math.h>

#define NALPH 128
#define NEMB  128
#define NST   512
#define BATCH 256
#define TLEN  256
#define FANIN 640   // NEMB + NST

#if __has_builtin(__builtin_amdgcn_sdot4)
#define SDOT4(a, b, c) __builtin_amdgcn_sdot4((a), (b), (c), false)
#else
__device__ __forceinline__ int SDOT4(int a, int b, int c) {
  c += (int)(signed char)(a)       * (int)(signed char)(b);
  c += (int)(signed char)(a >> 8)  * (int)(signed char)(b >> 8);
  c += (int)(signed char)(a >> 16) * (int)(signed char)(b >> 16);
  c += (int)(signed char)(a >> 24) * (int)(signed char)(b >> 24);
  return c;
}
#endif

// ---------------------------------------------------------------------------
// k_prep (896 blocks x 256 thr):
//  [0,256)    G[tok*512+n] = b_in[n] + sum_e emb[tok,e]*W_in[n,e]  (fp32 exact)
//  [256,768)  W_s row n quant -> Wq2[j*1024 + h*512 + n]: dword j of K-half h
//             (thread t = h*512+n in k_rec loads Wq2[j*1024+t] coalesced),
//             Sd[n] = rowmax/16129
//  [768,896)  W_out row-quant: WoQ[j*128+a] = pack4 i8, So[a] = mx/16129
// ---------------------------------------------------------------------------
__global__ __launch_bounds__(256) void k_prep(
    const float* __restrict__ emb, const float* __restrict__ W_in,
    const float* __restrict__ b_in, const float* __restrict__ W_out,
    float* __restrict__ G, int* __restrict__ Wq2, float* __restrict__ Sd,
    int* __restrict__ WoQ, float* __restrict__ So)
{
  int bid = blockIdx.x, tid = threadIdx.x;
  if (bid < 256) {
    int idx = bid * 256 + tid;           // tok*512 + n
    int tok = idx >> 9, n = idx & 511;
    const float* er = emb + tok * NEMB;
    const float* wr = W_in + (size_t)n * FANIN;
    float acc = b_in[n];
#pragma unroll 8
    for (int e = 0; e < NEMB; ++e) acc += er[e] * wr[e];
    G[idx] = acc;
  } else if (bid < 768) {
    int n = bid - 256;                   // W_s row
    __shared__ float smax[128];
    float lw[4]; float m = 0.f;
    if (tid < 128) {
      const float* wr = W_in + (size_t)n * FANIN + NEMB + tid * 4;
#pragma unroll
      for (int i = 0; i < 4; ++i) { lw[i] = wr[i]; m = fmaxf(m, fabsf(lw[i])); }
      smax[tid] = m;
    }
    __syncthreads();
    for (int s2 = 64; s2 > 0; s2 >>= 1) {
      if (tid < s2) smax[tid] = fmaxf(smax[tid], smax[tid + s2]);
      __syncthreads();
    }
    float mx = smax[0];
    if (tid < 128) {
      float r = 127.f / mx;
      uint32_t pk = 0;
#pragma unroll
      for (int i = 0; i < 4; ++i) {
        int qv = (int)rintf(lw[i] * r);
        qv = qv < -127 ? -127 : (qv > 127 ? 127 : qv);
        pk |= (uint32_t)(qv & 0xff) << (8 * i);
      }
      int h = tid >> 6, j = tid & 63;    // byte range tid*4 -> K-half h, dword j
      Wq2[j * 1024 + h * 512 + n] = (int)pk;
    }
    if (tid == 0) Sd[n] = mx / 16129.0f;
  } else {
    int a = bid - 768;                   // W_out row
    __shared__ float smax[128];
    float lw[4]; float m = 0.f;
    if (tid < 128) {
      const float* wr = W_out + (size_t)a * NST + tid * 4;
#pragma unroll
      for (int i = 0; i < 4; ++i) { lw[i] = wr[i]; m = fmaxf(m, fabsf(lw[i])); }
      smax[tid] = m;
    }
    __syncthreads();
    for (int s2 = 64; s2 > 0; s2 >>= 1) {
      if (tid < s2) smax[tid] = fmaxf(smax[tid], smax[tid + s2]);
      __syncthreads();
    }
    float mx = smax[0];
    if (tid < 128) {
      float r = 127.f / mx;
      uint32_t pk = 0;
#pragma unroll
      for (int i = 0; i < 4; ++i) {
        int qv = (int)rintf(lw[i] * r);
        qv = qv < -127 ? -127 : (qv > 127 ? 127 : qv);
        pk |= (uint32_t)(qv & 0xff) << (8 * i);
      }
      WoQ[tid * 128 + a] = (int)pk;      // k_out reads WoQ[j*128+a] coalesced
    }
    if (tid == 0) So[a] = mx / 16129.0f;
  }
}

// ---------------------------------------------------------------------------
// k_rec: 256 blocks x 1024 threads (16 waves, 4/EU). WAVE-level K-split:
// thread t -> col n = t&511, K-half h = t>>9 (wave-uniform!). wq[64] dwords
// register-resident. Per step: 16 broadcast ds_read_b128 (wave-uniform addr,
// conflict-free -- R8's proven pattern) + 64 sdot4 in 4 chains. Upper waves
// publish partial (1 coalesced ds_write_b32); barrier; lower waves add
// partner partial + activation + publish q8; barrier. Integer reorder only
// -> bit-identical to R8.
// ---------------------------------------------------------------------------
__global__ __launch_bounds__(1024, 4) void k_rec(
    const int* __restrict__ w, const float* __restrict__ G,
    const int* __restrict__ Wq2, const float* __restrict__ Sd,
    signed char* __restrict__ qstates)
{
  __shared__ __align__(16) signed char qs[2][NST];
  __shared__ int pr[NST];
  int t = threadIdx.x;
  int row = blockIdx.x;
  int h = t >> 9;                        // K-half (uniform per wave)
  int n = t & 511;                       // column
  int h256 = h << 8;

  int wq[64];
#pragma unroll
  for (int j = 0; j < 64; ++j) wq[j] = Wq2[j * 1024 + t];   // coalesced
  float dn = Sd[n];

  if (t < 128) ((int*)&qs[0][0])[t] = 0;
  __syncthreads();

  const int* wr = w + row * TLEN;
  signed char* qrow = qstates + (size_t)row * TLEN * NST;

  float g = 0.f;
  if (t < 512) g = G[wr[0] * NST + n];   // wave-uniform branch
  int p = 0;
  for (int tt = 0; tt < TLEN; ++tt) {
    int tok_n = (tt < TLEN - 1) ? wr[tt + 1] : 0;
    float g_n = 0.f;
    if (t < 512) g_n = G[tok_n * NST + n];  // prefetch next fin (uniform branch)

    const int4* sp = (const int4*)(&qs[p][0] + h256);
    int a0 = 0, a1 = 0, a2 = 0, a3 = 0;  // 4 independent chains, 16 deep
#pragma unroll
    for (int j = 0; j < 4; ++j) {
      int4 s0 = sp[4 * j + 0];           // broadcast b128, conflict-free
      int4 s1 = sp[4 * j + 1];
      int4 s2 = sp[4 * j + 2];
      int4 s3 = sp[4 * j + 3];
      a0 = SDOT4(wq[16 * j +  0], s0.x, a0);
      a1 = SDOT4(wq[16 * j +  1], s0.y, a1);
      a2 = SDOT4(wq[16 * j +  2], s0.z, a2);
      a3 = SDOT4(wq[16 * j +  3], s0.w, a3);
      a0 = SDOT4(wq[16 * j +  4], s1.x, a0);
      a1 = SDOT4(wq[16 * j +  5], s1.y, a1);
      a2 = SDOT4(wq[16 * j +  6], s1.z, a2);
      a3 = SDOT4(wq[16 * j +  7], s1.w, a3);
      a0 = SDOT4(wq[16 * j +  8], s2.x, a0);
      a1 = SDOT4(wq[16 * j +  9], s2.y, a1);
      a2 = SDOT4(wq[16 * j + 10], s2.z, a2);
      a3 = SDOT4(wq[16 * j + 11], s2.w, a3);
      a0 = SDOT4(wq[16 * j + 12], s3.x, a0);
      a1 = SDOT4(wq[16 * j + 13], s3.y, a1);
      a2 = SDOT4(wq[16 * j + 14], s3.z, a2);
      a3 = SDOT4(wq[16 * j + 15], s3.w, a3);
    }
    int ar = (a0 + a1) + (a2 + a3);
    if (t >= 512) pr[n] = ar;            // coalesced ds_write_b32 (2-way, free)
    __syncthreads();                     // barrier A: partials visible

    if (t < 512) {
      int acc = ar + pr[n];              // coalesced ds_read_b32
      float a = fmaf((float)acc, dn, g);
      float e = __expf(2.f * a);         // tanh = 1 - 2/(e^(2a)+1); inf-safe
      float s = fmaf(-2.f, __builtin_amdgcn_rcpf(e + 1.f), 1.f);
      int q8 = (int)rintf(s * 127.f);
      qs[p ^ 1][n] = (signed char)q8;
      qrow[(size_t)tt * NST + n] = (signed char)q8;
      g = g_n;
    }
    __syncthreads();                     // barrier B: new state visible
    p ^= 1;
  }
}

// ---------------------------------------------------------------------------
// k_out_i8 (verbatim R8, proven): y[bt,a] = b_out[a] + So[a]*sum_k q*qw
// 2048 blocks x 256 thr. Block: 32 bt-rows x 128 a. LDS-staged states,
// broadcast b128 reads, 16 sdot4 per j4.
// ---------------------------------------------------------------------------
__global__ __launch_bounds__(256) void k_out_i8(
    const signed char* __restrict__ qstates, const int* __restrict__ WoQ,
    const float* __restrict__ So, const float* __restrict__ b_out,
    float* __restrict__ y)
{
  __shared__ __align__(16) int sl[32 * 128];   // 16 KB
  int tid = threadIdx.x;
  size_t bt0 = (size_t)blockIdx.x * 32;
  const int4* gp = (const int4*)(qstates + bt0 * NST);
  int4* slp = (int4*)sl;
#pragma unroll
  for (int i = 0; i < 4; ++i) slp[tid + 256 * i] = gp[tid + 256 * i];
  __syncthreads();

  int a0 = tid & 63, gidx = tid >> 6;    // gidx uniform per wave
  const int* slg = sl + gidx * 8 * 128;
  int acc0[8], acc1[8];
#pragma unroll
  for (int r = 0; r < 8; ++r) { acc0[r] = 0; acc1[r] = 0; }

  for (int j4 = 0; j4 < 32; ++j4) {
    int w00 = WoQ[(4 * j4 + 0) * 128 + a0];
    int w01 = WoQ[(4 * j4 + 0) * 128 + a0 + 64];
    int w10 = WoQ[(4 * j4 + 1) * 128 + a0];
    int w11 = WoQ[(4 * j4 + 1) * 128 + a0 + 64];
    int w20 = WoQ[(4 * j4 + 2) * 128 + a0];
    int w21 = WoQ[(4 * j4 + 2) * 128 + a0 + 64];
    int w30 = WoQ[(4 * j4 + 3) * 128 + a0];
    int w31 = WoQ[(4 * j4 + 3) * 128 + a0 + 64];
#pragma unroll
    for (int r = 0; r < 8; ++r) {
      int4 s = *(const int4*)&slg[r * 128 + 4 * j4];  // broadcast b128
      acc0[r] = SDOT4(w00, s.x, acc0[r]);
      acc1[r] = SDOT4(w01, s.x, acc1[r]);
      acc0[r] = SDOT4(w10, s.y, acc0[r]);
      acc1[r] = SDOT4(w11, s.y, acc1[r]);
      acc0[r] = SDOT4(w20, s.z, acc0[r]);
      acc1[r] = SDOT4(w21, s.z, acc1[r]);
      acc0[r] = SDOT4(w30, s.w, acc0[r]);
      acc1[r] = SDOT4(w31, s.w, acc1[r]);
    }
  }

  float s0 = So[a0], s1 = So[a0 + 64];
  float b0 = b_out[a0], b1 = b_out[a0 + 64];
#pragma unroll
  for (int r = 0; r < 8; ++r) {
    size_t rowb = (bt0 + gidx * 8 + r) * 128;
    y[rowb + a0]      = (float)acc0[r] * s0 + b0;
    y[rowb + a0 + 64] = (float)acc1[r] * s1 + b1;
  }
}

// ---------------------------------------------------------------------------
extern "C" void kernel_launch(void* const* d_in, const int* in_sizes, int n_in,
                              void* d_out, int out_size, void* d_ws, size_t ws_size,
                              hipStream_t stream) {
  const int*   w     = (const int*)d_in[0];
  const float* emb   = (const float*)d_in[1];
  const float* W_in  = (const float*)d_in[2];
  const float* b_in  = (const float*)d_in[3];
  const float* W_out = (const float*)d_in[4];
  const float* b_out = (const float*)d_in[5];
  float* y = (float*)d_out;

  char* ws = (char*)d_ws;
  float*       G       = (float*)ws;                        // 256 KB
  int*         Wq2     = (int*)(ws + (256 << 10));          // 256 KB
  float*       Sd      = (float*)(ws + (512 << 10));        // 2 KB
  int*         WoQ     = (int*)(ws + (576 << 10));          // 64 KB
  float*       So      = (float*)(ws + (640 << 10));        // 0.5 KB
  signed char* qstates = (signed char*)(ws + (1024 << 10)); // 32 MB i8

  k_prep  <<<896, 256, 0, stream>>>(emb, W_in, b_in, W_out, G, Wq2, Sd, WoQ, So);
  k_rec   <<<BATCH, 1024, 0, stream>>>(w, G, Wq2, Sd, qstates);
  k_out_i8<<<BATCH * TLEN / 32, 256, 0, stream>>>(qstates, WoQ, So, b_out, y);
}

// Round 11
// 337.163 us; speedup vs baseline: 1.2328x; 1.0505x over previous
//
#include <hip/hip_runtime.h>
#include <stdint.h>
#include <math.h>

#define NALPH 128
#define NEMB  128
#define NST   512
#define BATCH 256
#define TLEN  256
#define FANIN 640   // NEMB + NST

#if __has_builtin(__builtin_amdgcn_sdot4)
#define SDOT4(a, b, c) __builtin_amdgcn_sdot4((a), (b), (c), false)
#else
__device__ __forceinline__ int SDOT4(int a, int b, int c) {
  c += (int)(signed char)(a)       * (int)(signed char)(b);
  c += (int)(signed char)(a >> 8)  * (int)(signed char)(b >> 8);
  c += (int)(signed char)(a >> 16) * (int)(signed char)(b >> 16);
  c += (int)(signed char)(a >> 24) * (int)(signed char)(b >> 24);
  return c;
}
#endif

#if __has_builtin(__builtin_amdgcn_mfma_i32_16x16x64_i8)
#define HAVE_I8MFMA 1
typedef __attribute__((ext_vector_type(4))) int i32x4;
#else
#define HAVE_I8MFMA 0
#endif

// ---------------------------------------------------------------------------
// k_prep (896 blocks x 256 thr) — R8 layout + Wo_frag emission:
//  [0,256)    G[tok*512+n] = b_in[n] + sum_e emb[tok,e]*W_in[n,e]  (fp32 exact)
//  [256,768)  W_s row-quant: WqT[kg*512+n] = pack4 i8, Sd[n] = mx/16129
//  [768,896)  W_out row-quant: WoQ[j*128+a] (fallback) AND MFMA B-frag order
//             WoF[((ta*8+c)*64+lane)*4+d], So[a] = mx/16129
// ---------------------------------------------------------------------------
__global__ __launch_bounds__(256) void k_prep(
    const float* __restrict__ emb, const float* __restrict__ W_in,
    const float* __restrict__ b_in, const float* __restrict__ W_out,
    float* __restrict__ G, int* __restrict__ WqT, float* __restrict__ Sd,
    int* __restrict__ WoQ, int* __restrict__ WoF, float* __restrict__ So)
{
  int bid = blockIdx.x, tid = threadIdx.x;
  if (bid < 256) {
    int idx = bid * 256 + tid;           // tok*512 + n
    int tok = idx >> 9, n = idx & 511;
    const float* er = emb + tok * NEMB;
    const float* wr = W_in + (size_t)n * FANIN;
    float acc = b_in[n];
#pragma unroll 8
    for (int e = 0; e < NEMB; ++e) acc += er[e] * wr[e];
    G[idx] = acc;
  } else if (bid < 768) {
    int n = bid - 256;                   // W_s row
    __shared__ float smax[128];
    float lw[4]; float m = 0.f;
    if (tid < 128) {
      const float* wr = W_in + (size_t)n * FANIN + NEMB + tid * 4;
#pragma unroll
      for (int i = 0; i < 4; ++i) { lw[i] = wr[i]; m = fmaxf(m, fabsf(lw[i])); }
      smax[tid] = m;
    }
    __syncthreads();
    for (int s2 = 64; s2 > 0; s2 >>= 1) {
      if (tid < s2) smax[tid] = fmaxf(smax[tid], smax[tid + s2]);
      __syncthreads();
    }
    float mx = smax[0];
    if (tid < 128) {
      float r = 127.f / mx;
      uint32_t pk = 0;
#pragma unroll
      for (int i = 0; i < 4; ++i) {
        int qv = (int)rintf(lw[i] * r);
        qv = qv < -127 ? -127 : (qv > 127 ? 127 : qv);
        pk |= (uint32_t)(qv & 0xff) << (8 * i);
      }
      WqT[tid * NST + n] = (int)pk;      // k_rec reads WqT[j*512+n] coalesced
    }
    if (tid == 0) Sd[n] = mx / 16129.0f;
  } else {
    int a = bid - 768;                   // W_out row
    __shared__ float smax[128];
    float lw[4]; float m = 0.f;
    if (tid < 128) {
      const float* wr = W_out + (size_t)a * NST + tid * 4;
#pragma unroll
      for (int i = 0; i < 4; ++i) { lw[i] = wr[i]; m = fmaxf(m, fabsf(lw[i])); }
      smax[tid] = m;
    }
    __syncthreads();
    for (int s2 = 64; s2 > 0; s2 >>= 1) {
      if (tid < s2) smax[tid] = fmaxf(smax[tid], smax[tid + s2]);
      __syncthreads();
    }
    float mx = smax[0];
    if (tid < 128) {
      float r = 127.f / mx;
      uint32_t pk = 0;
#pragma unroll
      for (int i = 0; i < 4; ++i) {
        int qv = (int)rintf(lw[i] * r);
        qv = qv < -127 ? -127 : (qv > 127 ? 127 : qv);
        pk |= (uint32_t)(qv & 0xff) << (8 * i);
      }
      WoQ[tid * 128 + a] = (int)pk;      // fallback k_out layout
      // MFMA B-frag order: kd = tid -> chunk c, sublane hi, dword d
      int kd = tid;
      int c = kd >> 4, hi = (kd >> 2) & 3, d = kd & 3;
      int lane = hi * 16 + (a & 15), ta = a >> 4;
      WoF[(((ta * 8 + c) * 64) + lane) * 4 + d] = (int)pk;
    }
    if (tid == 0) So[a] = mx / 16129.0f;
  }
}

// ---------------------------------------------------------------------------
// k_rec — VERBATIM R8 (measured 247.9 us): 256 blocks x 512 threads, W_s i8
// register-resident (128 dwords), 32 broadcast ds_read_b128 + 128 sdot4 in 4
// chains, one barrier/step, i8 state out.
// ---------------------------------------------------------------------------
__global__ __launch_bounds__(512, 2) void k_rec(
    const int* __restrict__ w, const float* __restrict__ G,
    const int* __restrict__ WqT, const float* __restrict__ Sd,
    signed char* __restrict__ qstates)
{
  __shared__ __align__(16) signed char qs[2][NST];
  int tid = threadIdx.x;
  int row = blockIdx.x;

  int wq[128];
#pragma unroll
  for (int j = 0; j < 128; ++j) wq[j] = WqT[j * NST + tid];  // coalesced
  float dn = Sd[tid];

  qs[0][tid] = 0;
  __syncthreads();

  const int* wr = w + row * TLEN;
  signed char* qrow = qstates + (size_t)row * TLEN * NST + tid;

  float g = G[wr[0] * NST + tid];
  int p = 0;
  for (int t = 0; t < TLEN; ++t) {
    int tok_n = (t < TLEN - 1) ? wr[t + 1] : 0;
    float g_n = G[tok_n * NST + tid];    // prefetch next step's fin
    const int4* sp = (const int4*)qs[p];
    int a0 = 0, a1 = 0, a2 = 0, a3 = 0;  // 4 independent chains
#pragma unroll
    for (int j = 0; j < 8; ++j) {
      int4 s0 = sp[4 * j + 0];
      int4 s1 = sp[4 * j + 1];
      int4 s2 = sp[4 * j + 2];
      int4 s3 = sp[4 * j + 3];
      a0 = SDOT4(wq[16 * j +  0], s0.x, a0);
      a1 = SDOT4(wq[16 * j +  1], s0.y, a1);
      a2 = SDOT4(wq[16 * j +  2], s0.z, a2);
      a3 = SDOT4(wq[16 * j +  3], s0.w, a3);
      a0 = SDOT4(wq[16 * j +  4], s1.x, a0);
      a1 = SDOT4(wq[16 * j +  5], s1.y, a1);
      a2 = SDOT4(wq[16 * j +  6], s1.z, a2);
      a3 = SDOT4(wq[16 * j +  7], s1.w, a3);
      a0 = SDOT4(wq[16 * j +  8], s2.x, a0);
      a1 = SDOT4(wq[16 * j +  9], s2.y, a1);
      a2 = SDOT4(wq[16 * j + 10], s2.z, a2);
      a3 = SDOT4(wq[16 * j + 11], s2.w, a3);
      a0 = SDOT4(wq[16 * j + 12], s3.x, a0);
      a1 = SDOT4(wq[16 * j + 13], s3.y, a1);
      a2 = SDOT4(wq[16 * j + 14], s3.z, a2);
      a3 = SDOT4(wq[16 * j + 15], s3.w, a3);
    }
    int acc = (a0 + a1) + (a2 + a3);
    float a = g + (float)acc * dn;
    a = fminf(fmaxf(a, -15.f), 15.f);
    float e = __expf(2.f * a);           // tanh = 1 - 2/(e^(2a)+1)
    float s = fmaf(-2.f, __builtin_amdgcn_rcpf(e + 1.f), 1.f);
    signed char q8 = (signed char)(int)rintf(s * 127.f);
    qrow[(size_t)t * NST] = q8;
    qs[p ^ 1][tid] = q8;
    __syncthreads();
    g = g_n;
    p ^= 1;
  }
}

#if HAVE_I8MFMA
// ---------------------------------------------------------------------------
// k_out_mfma (i8): y[bt,a] = b_out[a] + So[a]*sum_k qs[bt,k]*qw[a,k]
// 1024 blocks x 256 thr (4 waves). Wave: 16 bt-rows x 128 a.
// mfma_i32_16x16x64_i8: A[m=l15][k=hi*16+j] = states int4 (8 chunks resident),
// B[n=l15][k=hi*16+j] = WoF int4 (frag-ordered by prep), D: col=l15 (a),
// row=hi*4+reg (bt). Accumulators bit-identical to k_out_i8's integer dots.
// ---------------------------------------------------------------------------
__global__ __launch_bounds__(256) void k_out_mfma(
    const signed char* __restrict__ qstates, const int* __restrict__ WoF,
    const float* __restrict__ So, const float* __restrict__ b_out,
    float* __restrict__ y)
{
  int tid = threadIdx.x;
  int lane = tid & 63, wv = tid >> 6;
  int l15 = lane & 15, hi = lane >> 4;
  size_t bt0 = (size_t)blockIdx.x * 64 + (size_t)wv * 16;

  const signed char* abase = qstates + (bt0 + l15) * NST + hi * 16;
  i32x4 A[8];
#pragma unroll
  for (int c = 0; c < 8; ++c) A[c] = *(const i32x4*)(abase + c * 64);

  const i32x4* wf = (const i32x4*)WoF;
#pragma unroll
  for (int ta = 0; ta < 8; ++ta) {
    const i32x4* bbase = wf + (size_t)ta * 8 * 64 + lane;
    i32x4 acc = {0, 0, 0, 0};
#pragma unroll
    for (int c = 0; c < 8; ++c)
      acc = __builtin_amdgcn_mfma_i32_16x16x64_i8(A[c], bbase[c * 64], acc, 0, 0, 0);
    int a = ta * 16 + l15;
    float s = So[a], b = b_out[a];
    float* yb = y + (bt0 + hi * 4) * 128 + a;
#pragma unroll
    for (int r = 0; r < 4; ++r) yb[(size_t)r * 128] = (float)acc[r] * s + b;
  }
}
#endif

// ---------------------------------------------------------------------------
// k_out_i8 (verbatim R8, proven) — fallback
// ---------------------------------------------------------------------------
__global__ __launch_bounds__(256) void k_out_i8(
    const signed char* __restrict__ qstates, const int* __restrict__ WoQ,
    const float* __restrict__ So, const float* __restrict__ b_out,
    float* __restrict__ y)
{
  __shared__ __align__(16) int sl[32 * 128];   // 16 KB
  int tid = threadIdx.x;
  size_t bt0 = (size_t)blockIdx.x * 32;
  const int4* gp = (const int4*)(qstates + bt0 * NST);
  int4* slp = (int4*)sl;
#pragma unroll
  for (int i = 0; i < 4; ++i) slp[tid + 256 * i] = gp[tid + 256 * i];
  __syncthreads();

  int a0 = tid & 63, gidx = tid >> 6;
  const int* slg = sl + gidx * 8 * 128;
  int acc0[8], acc1[8];
#pragma unroll
  for (int r = 0; r < 8; ++r) { acc0[r] = 0; acc1[r] = 0; }

  for (int j4 = 0; j4 < 32; ++j4) {
    int w00 = WoQ[(4 * j4 + 0) * 128 + a0];
    int w01 = WoQ[(4 * j4 + 0) * 128 + a0 + 64];
    int w10 = WoQ[(4 * j4 + 1) * 128 + a0];
    int w11 = WoQ[(4 * j4 + 1) * 128 + a0 + 64];
    int w20 = WoQ[(4 * j4 + 2) * 128 + a0];
    int w21 = WoQ[(4 * j4 + 2) * 128 + a0 + 64];
    int w30 = WoQ[(4 * j4 + 3) * 128 + a0];
    int w31 = WoQ[(4 * j4 + 3) * 128 + a0 + 64];
#pragma unroll
    for (int r = 0; r < 8; ++r) {
      int4 s = *(const int4*)&slg[r * 128 + 4 * j4];
      acc0[r] = SDOT4(w00, s.x, acc0[r]);
      acc1[r] = SDOT4(w01, s.x, acc1[r]);
      acc0[r] = SDOT4(w10, s.y, acc0[r]);
      acc1[r] = SDOT4(w11, s.y, acc1[r]);
      acc0[r] = SDOT4(w20, s.z, acc0[r]);
      acc1[r] = SDOT4(w21, s.z, acc1[r]);
      acc0[r] = SDOT4(w30, s.w, acc0[r]);
      acc1[r] = SDOT4(w31, s.w, acc1[r]);
    }
  }

  float s0 = So[a0], s1 = So[a0 + 64];
  float b0 = b_out[a0], b1 = b_out[a0 + 64];
#pragma unroll
  for (int r = 0; r < 8; ++r) {
    size_t rowb = (bt0 + gidx * 8 + r) * 128;
    y[rowb + a0]      = (float)acc0[r] * s0 + b0;
    y[rowb + a0 + 64] = (float)acc1[r] * s1 + b1;
  }
}

// ---------------------------------------------------------------------------
extern "C" void kernel_launch(void* const* d_in, const int* in_sizes, int n_in,
                              void* d_out, int out_size, void* d_ws, size_t ws_size,
                              hipStream_t stream) {
  const int*   w     = (const int*)d_in[0];
  const float* emb   = (const float*)d_in[1];
  const float* W_in  = (const float*)d_in[2];
  const float* b_in  = (const float*)d_in[3];
  const float* W_out = (const float*)d_in[4];
  const float* b_out = (const float*)d_in[5];
  float* y = (float*)d_out;

  char* ws = (char*)d_ws;
  float*       G       = (float*)ws;                        // 256 KB
  int*         WqT     = (int*)(ws + (256 << 10));          // 256 KB
  float*       Sd      = (float*)(ws + (512 << 10));        // 2 KB
  int*         WoQ     = (int*)(ws + (576 << 10));          // 64 KB
  float*       So      = (float*)(ws + (640 << 10));        // 0.5 KB
  int*         WoF     = (int*)(ws + (704 << 10));          // 32 KB frag-order
  signed char* qstates = (signed char*)(ws + (1024 << 10)); // 32 MB i8

  k_prep<<<896, 256, 0, stream>>>(emb, W_in, b_in, W_out, G, WqT, Sd, WoQ, WoF, So);
  k_rec <<<BATCH, 512, 0, stream>>>(w, G, WqT, Sd, qstates);
#if HAVE_I8MFMA
  k_out_mfma<<<BATCH * TLEN / 64, 256, 0, stream>>>(qstates, WoF, So, b_out, y);
#else
  k_out_i8<<<BATCH * TLEN / 32, 256, 0, stream>>>(qstates, WoQ, So, b_out, y);
#endif
}